// Round 1
// 1315.548 us; speedup vs baseline: 1.1166x; 1.1166x over previous
//
#include <hip/hip_runtime.h>
#include <hip/hip_bf16.h>
#include <math.h>

#define B_  4
#define T_  1024
#define V_  32000
#define D_  1024
#define H_  16
#define DK_ 64
#define BT_ (B_*T_)

typedef unsigned short u16;
typedef short short8 __attribute__((ext_vector_type(8)));
typedef float f32x4 __attribute__((ext_vector_type(4)));

__device__ __forceinline__ float bf2f(u16 u) {
  union { unsigned int i; float f; } v; v.i = ((unsigned int)u) << 16; return v.f;
}
__device__ __forceinline__ u16 f2bf(float f) {
  union { float f; unsigned int i; } v; v.f = f;
  unsigned int x = v.i;
  return (u16)((x + 0x7fffu + ((x >> 16) & 1u)) >> 16);   // RNE
}

__device__ __forceinline__ void gload16(const void* g, void* l) {
  __builtin_amdgcn_global_load_lds((const __attribute__((address_space(1))) void*)g,
                                   (__attribute__((address_space(3))) void*)l, 16, 0, 0);
}

// ---------------- embedding: x = tok_emb[idx]*32 + pos_emb, -> bf16 ----------------
__global__ void embed_kernel(const int* __restrict__ inputs, const float* __restrict__ tok_emb,
                             const float* __restrict__ pos_emb, u16* __restrict__ xb) {
  int row = blockIdx.x;                 // 0..4095 (= b*T + t)
  int t = row & (T_ - 1);
  int tok = inputs[row];
  const float* te = tok_emb + (size_t)tok * D_;
  const float* pe = pos_emb + (size_t)t * D_;
  u16* out = xb + (size_t)row * D_;
  for (int d = threadIdx.x; d < D_; d += blockDim.x)
    out[d] = f2bf(te[d] * 32.0f + pe[d]);
}

// ---------------- pack Wq/Wk/Wv [H,D,DK] f32 -> Wt [N=H*DK][D] bf16 ----------------
__global__ void pack_w_kernel(const float* __restrict__ W, u16* __restrict__ Wt) {
  int n = blockIdx.x;                   // 0..1023
  int h = n >> 6, k = n & 63;
  const float* src = W + ((size_t)h * D_) * DK_ + k;
  u16* dst = Wt + (size_t)n * D_;
  for (int d = threadIdx.x; d < D_; d += blockDim.x)
    dst[d] = f2bf(src[(size_t)d * DK_]);
}

// ---------------- transpose Wo [D,V] f32 -> WoT [V,D] bf16 (LDS tiled) ----------------
__global__ __launch_bounds__(256) void transpose_wo_kernel(const float* __restrict__ Wo,
                                                           u16* __restrict__ WoT) {
  __shared__ u16 tile[64][66];
  int n0 = blockIdx.x * 64;             // V dim
  int d0 = blockIdx.y * 64;             // D dim
  int tx = threadIdx.x & 63, ty = threadIdx.x >> 6;
  #pragma unroll
  for (int i = 0; i < 64; i += 4) {
    int d = d0 + ty + i;
    tile[ty + i][tx] = f2bf(Wo[(size_t)d * V_ + n0 + tx]);
  }
  __syncthreads();
  #pragma unroll
  for (int i = 0; i < 64; i += 4) {
    int n = n0 + ty + i;
    WoT[(size_t)n * D_ + d0 + tx] = tile[tx][ty + i];
  }
}

// ---------------- GEMM (QKV): C = A[M,K] * Bt[N,K]^T, 128^2 tile ----------------
// MODE 1: Cout bf16 at [B,H,T,DK] from m=b*T+t, n=h*64+k, + bias[n]  (Q/K/V)
template<int MODE>
__global__ __launch_bounds__(256) void gemm_bt(const u16* __restrict__ A,
                                               const u16* __restrict__ Bt,
                                               const float* __restrict__ bias,
                                               void* __restrict__ Cout,
                                               int M, int N, int K) {
  __shared__ __align__(16) u16 As[128 * 32];
  __shared__ __align__(16) u16 Bs[128 * 32];
  int m0 = blockIdx.x * 128;
  int n0 = blockIdx.y * 128;
  int tid = threadIdx.x;
  int lane = tid & 63;
  int wave = tid >> 6;
  int wm = (wave >> 1) * 64, wn = (wave & 1) * 64;

  f32x4 acc[4][4] = {};

  int arow0 = tid >> 2;                 // staging row (+64 for 2nd issue)
  int acol  = (tid & 3) * 8;            // staging k-chunk
  const u16* Ag = A  + (size_t)(m0 + arow0) * K + acol;
  const u16* Bg = Bt + (size_t)(n0 + arow0) * K + acol;
  u16* Asl = As + tid * 8;              // byte ofs tid*16 = wave*1024 + lane*16
  u16* Bsl = Bs + tid * 8;

  int fr = lane & 15;
  int fk = (lane >> 4) * 8;

  for (int k0 = 0; k0 < K; k0 += 32) {
    gload16(Ag + k0, Asl);
    gload16(Ag + (size_t)64 * K + k0, Asl + 2048);
    gload16(Bg + k0, Bsl);
    gload16(Bg + (size_t)64 * K + k0, Bsl + 2048);
    __syncthreads();
    short8 af[4], bfg[4];
    #pragma unroll
    for (int i = 0; i < 4; i++) {
      af[i]  = *(const short8*)(As + (wm + i * 16 + fr) * 32 + fk);
      bfg[i] = *(const short8*)(Bs + (wn + i * 16 + fr) * 32 + fk);
    }
    #pragma unroll
    for (int i = 0; i < 4; i++)
      #pragma unroll
      for (int j = 0; j < 4; j++)
        acc[i][j] = __builtin_amdgcn_mfma_f32_16x16x32_bf16(af[i], bfg[j], acc[i][j], 0, 0, 0);
    __syncthreads();
  }

  #pragma unroll
  for (int i = 0; i < 4; i++) {
    int rowb = m0 + wm + i * 16 + (lane >> 4) * 4;
    #pragma unroll
    for (int j = 0; j < 4; j++) {
      int n = n0 + wn + j * 16 + (lane & 15);
      float bv = bias[n];
      #pragma unroll
      for (int r = 0; r < 4; r++) {
        int m = rowb + r;
        float v = acc[i][j][r] + bv;
        if (MODE == 0) {
          ((float*)Cout)[(size_t)m * N + n] = v;
        } else {
          int b = m >> 10, t = m & 1023, h = n >> 6, k = n & 63;
          ((u16*)Cout)[((((size_t)b * H_ + h) * T_) + t) * DK_ + k] = f2bf(v);
        }
      }
    }
  }
}

// ---------------- logits GEMM: 256x256 tile, BK=64, 8 waves, counted-vmcnt pipeline ----------------
// C[M=4096, N=32000] f32 = A[4096,1024]bf16 * Bt[32000,1024]^T + bias
// LDS layout is FRAGMENT-CONTIGUOUS: each 16x32 MFMA subtile stored in lane order, so
// every wave ds_read_b128 reads 1024 contiguous bytes -> zero bank conflicts, and
// global_load_lds (linear dest) works by permuting the per-lane *global* address.
#define G256_NT 16          // K/64
#define G256_NB 125         // N/256

// stage chunk c (0=A-lo,1=A-hi,2=B-lo,3=B-hi) of K-tile kt_ : 2 loads/thread
#define ISS(kt_, c_) do {                                                              \
    const int kk_ = (((kt_) & (G256_NT - 1)) << 6);                                    \
    const int pb_ = (kt_) & 1;                                                         \
    const u16* s0_ = (((c_) < 2) ? Ab : Bb) + ((size_t)((((c_) & 1) << 7)) << 10) + kk_;\
    u16* d0_ = &lds[pb_][((c_) < 2) ? 0 : 1][(((c_) & 1) ? 8192 : 0) + wl];            \
    gload16(s0_, d0_);                                                                 \
    gload16(s0_ + ((size_t)64 << 10), d0_ + 4096);                                     \
  } while (0)

#define MFMA_Q(MIOFF, NIOFF)                                                           \
  __builtin_amdgcn_s_setprio(1);                                                       \
  _Pragma("unroll")                                                                    \
  for (int mi = 0; mi < 4; ++mi) {                                                     \
    _Pragma("unroll")                                                                  \
    for (int ni = 0; ni < 2; ++ni) {                                                   \
      acc[(MIOFF)+mi][(NIOFF)+ni] = __builtin_amdgcn_mfma_f32_16x16x32_bf16(           \
          Af[mi][0], Bf[(NIOFF)+ni][0], acc[(MIOFF)+mi][(NIOFF)+ni], 0, 0, 0);         \
      acc[(MIOFF)+mi][(NIOFF)+ni] = __builtin_amdgcn_mfma_f32_16x16x32_bf16(           \
          Af[mi][1], Bf[(NIOFF)+ni][1], acc[(MIOFF)+mi][(NIOFF)+ni], 0, 0, 0);         \
    }                                                                                  \
  }                                                                                    \
  __builtin_amdgcn_s_setprio(0);

__global__ __launch_bounds__(512, 2) void gemm256(const u16* __restrict__ A,
                                                  const u16* __restrict__ Bt,
                                                  const float* __restrict__ bias,
                                                  float* __restrict__ C) {
  __shared__ __align__(16) u16 lds[2][2][16384];   // [buf][A|B][32KB as u16] = 128 KiB

  // XCD-bijective block swizzle (2000 % 8 == 0), n-fastest so each XCD keeps 2 A-panels hot
  int bid = blockIdx.x;
  int swz = (bid & 7) * (2000 / 8) + (bid >> 3);
  int mb = swz / G256_NB, nb = swz % G256_NB;
  int m0 = mb << 8, n0 = nb << 8;

  const int tid = threadIdx.x;
  const int w = tid >> 6, l = tid & 63;

  // staging geometry: thread covers row (w>>1)*16+(l&15), k (w&1)*32+(l>>4)*8 of each 128-row chunk
  const int rowS = ((w >> 1) << 4) + (l & 15);
  const int kS   = ((w & 1) << 5) + ((l >> 4) << 3);
  const int wl   = (w << 9) + (l << 3);            // u16 offset: wave*1024B + lane*16B

  const u16* Ab = A  + ((size_t)(m0 + rowS) << 10) + kS;
  const u16* Bb = Bt + ((size_t)(n0 + rowS) << 10) + kS;

  f32x4 acc[8][4] = {};

  // prologue: tile0 all 4 chunks + tile1 chunk0 (10 loads/thread in flight)
  ISS(0, 0); ISS(0, 1); ISS(0, 2); ISS(0, 3);
  ISS(1, 0);
  asm volatile("s_waitcnt vmcnt(2)" ::: "memory");  // tile0 fully staged, tile1-c0 in flight
  __builtin_amdgcn_s_barrier();

  #pragma unroll 2
  for (int kt = 0; kt < G256_NT; ++kt) {
    const int p = kt & 1;
    const u16* fA = &lds[p][0][((w >> 2) << 13) + (l << 3)];
    const u16* fB = &lds[p][1][((w & 3) << 12) + (l << 3)];
    short8 Af[4][2], Bf[4][2];

    // ---- phase 1: read A(mi0-3) + B(ni0-1), issue (t+1)A-hi, mfma quadrant (0,0)
    #pragma unroll
    for (int mi = 0; mi < 4; ++mi)
      #pragma unroll
      for (int s = 0; s < 2; ++s)
        Af[mi][s] = *(const short8*)(fA + ((mi * 2 + s) << 9));
    #pragma unroll
    for (int ni = 0; ni < 2; ++ni)
      #pragma unroll
      for (int s = 0; s < 2; ++s)
        Bf[ni][s] = *(const short8*)(fB + ((ni * 2 + s) << 9));
    ISS(kt + 1, 1);
    __builtin_amdgcn_s_barrier();
    MFMA_Q(0, 0)
    __builtin_amdgcn_s_barrier();

    // ---- phase 2: read B(ni2-3), issue (t+1)B-lo, mfma quadrant (0,2)
    #pragma unroll
    for (int ni = 2; ni < 4; ++ni)
      #pragma unroll
      for (int s = 0; s < 2; ++s)
        Bf[ni][s] = *(const short8*)(fB + ((ni * 2 + s) << 9));
    ISS(kt + 1, 2);
    __builtin_amdgcn_s_barrier();
    MFMA_Q(0, 2)
    __builtin_amdgcn_s_barrier();

    // ---- phase 3: read A(mi4-7), issue (t+1)B-hi, mfma quadrant (4,0)
    #pragma unroll
    for (int mi = 0; mi < 4; ++mi)
      #pragma unroll
      for (int s = 0; s < 2; ++s)
        Af[mi][s] = *(const short8*)(fA + (((4 + mi) * 2 + s) << 9));
    ISS(kt + 1, 3);
    __builtin_amdgcn_s_barrier();
    MFMA_Q(4, 0)
    __builtin_amdgcn_s_barrier();

    // ---- phase 4: issue (t+2)A-lo, mfma quadrant (4,2), counted vmcnt (never 0)
    ISS(kt + 2, 0);
    __builtin_amdgcn_s_barrier();
    MFMA_Q(4, 2)
    asm volatile("s_waitcnt vmcnt(2)" ::: "memory"); // next tile's 4 chunks landed; keep 1 chunk in flight
    __builtin_amdgcn_s_barrier();
  }

  // epilogue: C-layout col=lane&15, row=(lane>>4)*4+r
  const int mrow = m0 + ((w >> 2) << 7) + ((l >> 4) << 2);
  const int ncol = n0 + ((w & 3) << 6) + (l & 15);
  #pragma unroll
  for (int mi = 0; mi < 8; ++mi) {
    #pragma unroll
    for (int ni = 0; ni < 4; ++ni) {
      const int n = ncol + ni * 16;
      const float bv = bias[n];
      float* Crow = C + (size_t)(mrow + mi * 16) * V_ + n;
      #pragma unroll
      for (int r = 0; r < 4; ++r)
        Crow[(size_t)r * V_] = acc[mi][ni][r] + bv;
    }
  }
}

// ---------------- flash attention: Q,K,V [B,H,T,DK] bf16 -> O [BT, D] bf16 ----------------
__global__ __launch_bounds__(256) void flash_attn(const u16* __restrict__ Q,
                                                  const u16* __restrict__ Kw,
                                                  const u16* __restrict__ Vw,
                                                  u16* __restrict__ Oout) {
  int qt = blockIdx.x;                  // 0..15 (q tile of 64)
  int bh = blockIdx.y;                  // 0..63
  int b = bh >> 4, h = bh & 15;
  const u16* Qb = Q  + (size_t)bh * T_ * DK_;
  const u16* Kb = Kw + (size_t)bh * T_ * DK_;
  const u16* Vb = Vw + (size_t)bh * T_ * DK_;
  int q0 = qt * 64;

  __shared__ __align__(16) u16 Qs[64 * 64];
  __shared__ __align__(16) u16 Ks[32 * 64];   // [key][d]
  __shared__ __align__(16) u16 Vs[64 * 32];   // [d][key] (transposed)
  __shared__ __align__(16) u16 Ps[4][16 * 32];

  int tid = threadIdx.x, wave = tid >> 6, lane = tid & 63;
  int fr = lane & 15, fq = lane >> 4;

  {
    const u16* g = Qb + (size_t)(q0 + (tid >> 3)) * DK_ + (tid & 7) * 8;
    u16* l = Qs + tid * 8;
    gload16(g, l);
    gload16(g + 32 * DK_, l + 2048);
  }
  __syncthreads();
  short8 qf[2];
  #pragma unroll
  for (int c = 0; c < 2; c++)
    qf[c] = *(const short8*)(Qs + (wave * 16 + fr) * 64 + c * 32 + fq * 8);
  __syncthreads();

  float m_i[4], l_i[4];
  f32x4 o[4] = {};
  #pragma unroll
  for (int r = 0; r < 4; r++) { m_i[r] = -1e30f; l_i[r] = 0.f; }

  const float scale = 0.125f;           // 1/sqrt(64)
  int ntiles = (q0 + 63) / 32 + 1;

  for (int jt = 0; jt < ntiles; jt++) {
    int kb = jt * 32;
    gload16(Kb + (size_t)(kb + (tid >> 3)) * DK_ + (tid & 7) * 8, Ks + tid * 8);
    {
      int key = tid >> 3, d0v = (tid & 7) * 8;
      short8 vv = *(const short8*)(Vb + (size_t)(kb + key) * DK_ + d0v);
      #pragma unroll
      for (int j = 0; j < 8; j++)
        Vs[(d0v + j) * 32 + key] = ((const u16*)&vv)[j];
    }
    __syncthreads();

    short8 kf[2][2];
    #pragma unroll
    for (int t2 = 0; t2 < 2; t2++)
      #pragma unroll
      for (int c = 0; c < 2; c++)
        kf[t2][c] = *(const short8*)(Ks + (t2 * 16 + fr) * 64 + c * 32 + fq * 8);
    f32x4 zero = {0.f, 0.f, 0.f, 0.f};
    f32x4 s[2];
    #pragma unroll
    for (int t2 = 0; t2 < 2; t2++) {
      s[t2] = __builtin_amdgcn_mfma_f32_16x16x32_bf16(qf[0], kf[t2][0], zero, 0, 0, 0);
      s[t2] = __builtin_amdgcn_mfma_f32_16x16x32_bf16(qf[1], kf[t2][1], s[t2], 0, 0, 0);
    }

    float alpha_r[4], p0v[4], p1v[4];
    #pragma unroll
    for (int r = 0; r < 4; r++) {
      int qg = q0 + wave * 16 + fq * 4 + r;
      float s0 = s[0][r] * scale;
      float s1 = s[1][r] * scale;
      if (kb + fr > qg)      s0 = -1e30f;
      if (kb + 16 + fr > qg) s1 = -1e30f;
      float mx = fmaxf(s0, s1);
      mx = fmaxf(mx, __shfl_xor(mx, 1));
      mx = fmaxf(mx, __shfl_xor(mx, 2));
      mx = fmaxf(mx, __shfl_xor(mx, 4));
      mx = fmaxf(mx, __shfl_xor(mx, 8));
      float mn = fmaxf(m_i[r], mx);
      float p0 = __expf(s0 - mn), p1 = __expf(s1 - mn);
      float alpha = __expf(m_i[r] - mn);
      float psum = p0 + p1;
      psum += __shfl_xor(psum, 1);
      psum += __shfl_xor(psum, 2);
      psum += __shfl_xor(psum, 4);
      psum += __shfl_xor(psum, 8);
      l_i[r] = l_i[r] * alpha + psum;
      m_i[r] = mn;
      alpha_r[r] = alpha;
      p0v[r] = p0; p1v[r] = p1;
    }

    u16* Pw = Ps[wave];
    #pragma unroll
    for (int r = 0; r < 4; r++) {
      Pw[(fq * 4 + r) * 32 + fr]      = f2bf(p0v[r]);
      Pw[(fq * 4 + r) * 32 + 16 + fr] = f2bf(p1v[r]);
    }
    asm volatile("s_waitcnt lgkmcnt(0)" ::: "memory");
    short8 pf = *(const short8*)(Pw + fr * 32 + fq * 8);

    short8 vf[4];
    #pragma unroll
    for (int nt = 0; nt < 4; nt++)
      vf[nt] = *(const short8*)(Vs + (nt * 16 + fr) * 32 + fq * 8);

    #pragma unroll
    for (int nt = 0; nt < 4; nt++) {
      f32x4 c = o[nt];
      #pragma unroll
      for (int r = 0; r < 4; r++) c[r] *= alpha_r[r];
      o[nt] = __builtin_amdgcn_mfma_f32_16x16x32_bf16(pf, vf[nt], c, 0, 0, 0);
    }
    __syncthreads();
  }

  #pragma unroll
  for (int r = 0; r < 4; r++) l_i[r] = 1.0f / l_i[r];
  int trow = q0 + wave * 16 + fq * 4;
  #pragma unroll
  for (int nt = 0; nt < 4; nt++) {
    int d = h * 64 + nt * 16 + fr;
    #pragma unroll
    for (int r = 0; r < 4; r++) {
      int t = trow + r;
      Oout[((size_t)b * T_ + t) * D_ + d] = f2bf(o[nt][r] * l_i[r]);
    }
  }
}

// ---------------- loss: single-pass online softmax, float4 loads ----------------
__global__ __launch_bounds__(256) void row_loss_kernel(const float* __restrict__ logits,
                                                       const int* __restrict__ targets,
                                                       float* __restrict__ partial) {
  int row = blockIdx.x;
  int tid = threadIdx.x;
  const float4* p4 = (const float4*)(logits + (size_t)row * V_);
  float m = -1e30f, s = 0.f;
  for (int i = tid; i < V_ / 4; i += 256) {
    float4 v = p4[i];
    float cm = fmaxf(fmaxf(v.x, v.y), fmaxf(v.z, v.w));
    if (cm > m) { s *= __expf(m - cm); m = cm; }
    s += __expf(v.x - m) + __expf(v.y - m) + __expf(v.z - m) + __expf(v.w - m);
  }
  __shared__ float rm[256], rs[256];
  rm[tid] = m; rs[tid] = s; __syncthreads();
  for (int st = 128; st > 0; st >>= 1) {
    if (tid < st) {
      float m2 = rm[tid + st], s2 = rs[tid + st];
      float mn = fmaxf(rm[tid], m2);
      rs[tid] = rs[tid] * __expf(rm[tid] - mn) + s2 * __expf(m2 - mn);
      rm[tid] = mn;
    }
    __syncthreads();
  }
  if (tid == 0) {
    float lse = rm[0] + __logf(rs[0]);
    partial[row] = logits[(size_t)row * V_ + targets[row]] - lse;
  }
}

__global__ void final_loss_kernel(const float* __restrict__ partial, float* __restrict__ out_loss) {
  __shared__ float red[256];
  float s = 0.f;
  for (int i = threadIdx.x; i < BT_; i += 256) s += partial[i];
  red[threadIdx.x] = s; __syncthreads();
  for (int st = 128; st > 0; st >>= 1) {
    if (threadIdx.x < st) red[threadIdx.x] += red[threadIdx.x + st];
    __syncthreads();
  }
  if (threadIdx.x == 0) out_loss[0] = -red[0] / (float)BT_;
}

extern "C" void kernel_launch(void* const* d_in, const int* in_sizes, int n_in,
                              void* d_out, int out_size, void* d_ws, size_t ws_size,
                              hipStream_t stream) {
  const int*   inputs  = (const int*)d_in[0];
  const int*   targets = (const int*)d_in[1];
  const float* tok_emb = (const float*)d_in[2];
  const float* pos_emb = (const float*)d_in[3];
  const float* Wq = (const float*)d_in[4];
  const float* bq = (const float*)d_in[5];
  const float* Wk = (const float*)d_in[6];
  const float* bk = (const float*)d_in[7];
  const float* Wv = (const float*)d_in[8];
  const float* bv = (const float*)d_in[9];
  const float* Wo = (const float*)d_in[10];
  const float* bo = (const float*)d_in[11];

  char* w = (char*)d_ws;
  u16* xb   = (u16*)(w);                            //   8,388,608
  u16* WqT  = (u16*)(w + 8388608);                  //   2,097,152
  u16* WkT  = (u16*)(w + 10485760);
  u16* WvT  = (u16*)(w + 12582912);
  u16* WoT  = (u16*)(w + 14680064);                 //  65,536,000
  u16* Qw   = (u16*)(w + 80216064);                 //   8,388,608
  u16* Kw   = (u16*)(w + 88604672);
  u16* Vw   = (u16*)(w + 96993280);
  u16* AO   = (u16*)(w + 105381888);
  float* part = (float*)(w + 113770496);            //      16,384

  float* logits = (float*)d_out;
  float* loss   = logits + (size_t)BT_ * V_;

  embed_kernel<<<BT_, 256, 0, stream>>>(inputs, tok_emb, pos_emb, xb);
  pack_w_kernel<<<1024, 256, 0, stream>>>(Wq, WqT);
  pack_w_kernel<<<1024, 256, 0, stream>>>(Wk, WkT);
  pack_w_kernel<<<1024, 256, 0, stream>>>(Wv, WvT);
  transpose_wo_kernel<<<dim3(V_ / 64, D_ / 64), 256, 0, stream>>>(Wo, WoT);

  gemm_bt<1><<<dim3(BT_ / 128, D_ / 128), 256, 0, stream>>>(xb, WqT, bq, Qw, BT_, D_, D_);
  gemm_bt<1><<<dim3(BT_ / 128, D_ / 128), 256, 0, stream>>>(xb, WkT, bk, Kw, BT_, D_, D_);
  gemm_bt<1><<<dim3(BT_ / 128, D_ / 128), 256, 0, stream>>>(xb, WvT, bv, Vw, BT_, D_, D_);

  flash_attn<<<dim3(T_ / 64, B_ * H_), 256, 0, stream>>>(Qw, Kw, Vw, AO);

  gemm256<<<(BT_ / 256) * (V_ / 256), 512, 0, stream>>>(AO, WoT, bo, logits);

  row_loss_kernel<<<BT_, 256, 0, stream>>>(logits, targets, part);
  final_loss_kernel<<<1, 256, 0, stream>>>(part, loss);
}